// Round 7
// baseline (84.327 us; speedup 1.0000x reference)
//
#include <hip/hip_runtime.h>

// Problem constants (from reference init_kwargs)
#define BB   64
#define KP   21
#define HH   256
#define KS   9
#define PADK 4   // KS/2

#define NPLANES       (BB * KP)                    // 1344
#define F4_PER_PLANE  (HH * HH / 4)                // 16384
#define NBLOCKS       2048                         // 8 blocks/CU -> 32 waves/CU
#define THREADS       256
#define NTH_TOTAL     (NBLOCKS * THREADS)          // 524288 float4 / sweep (8 MB)
#define F4_TOTAL      (NPLANES * F4_PER_PLANE)     // 22,020,096
#define NSWEEP        (F4_TOTAL / NTH_TOTAL)       // 42

typedef float vfloat4 __attribute__((ext_vector_type(4)));

// Fused zero + patch, GRID-STRIDE zero stream (rocclr-fill-style sweeping
// window: whole device writes one contiguous 8 MB region at a time -> DRAM
// row-sequential, vs. 2048 scattered frontiers in previous variants).
//
// Ownership under grid-stride: float4 index a belongs to block
// (a % 524288)/256. Plane p occupies mod-window (p%32)*16384+off, so block b
// owns only planes p ≡ (b>>6) (mod 32), rows [(b&63)*4, (b&63)*4+4).
// Phase 2 (after __syncthreads: compiler drains vmcnt(0) before s_barrier,
// ordering zero stores before patch stores at same addresses — correctness
// of this mechanism proven in rounds 5/6).
__global__ __launch_bounds__(THREADS)
void heatmap_sweep_kernel(const int* __restrict__ x,
                          const float* __restrict__ k2d,
                          vfloat4* __restrict__ out) {
    const int t = threadIdx.x;
    const int b = blockIdx.x;

    // ---- phase 1: grid-stride zero sweep ----
    vfloat4* ptr = out + (b * THREADS + t);
#pragma unroll
    for (int it = 0; it < NSWEEP; ++it) {
        *ptr = (vfloat4)0.0f;          // wave: 1 KiB contiguous per store
        ptr += NTH_TOTAL;              // next 8 MB window
    }

    __syncthreads();

    // ---- phase 2: patch overwrite for addresses this block owns ----
    if (t < KS * KS) {
        const int dy  = t / KS;        // 0..8
        const int dx  = t - dy * KS;
        const int w   = b >> 6;        // plane residue class (0..31)
        const int rlo = (b & 63) * 4;  // my 4-row window within the plane
        const float wt = 10.0f * k2d[(KS - 1 - dy) * KS + (KS - 1 - dx)];
        for (int m = 0; m < NPLANES / 32; ++m) {   // 42 candidate planes
            const int pl = w + (m << 5);
            const int r = x[2 * pl];
            const int c = x[2 * pl + 1];
            const int i = r - PADK + dy;
            const int j = c - PADK + dx;
            if (i >= rlo && i < rlo + 4 && j >= 0 && j < HH) {
                ((float*)out)[(size_t)pl * (HH * HH) + i * HH + j] = wt;
            }
        }
    }
}

extern "C" void kernel_launch(void* const* d_in, const int* in_sizes, int n_in,
                              void* d_out, int out_size, void* d_ws, size_t ws_size,
                              hipStream_t stream) {
    const int*   x   = (const int*)d_in[0];    // [B, KP, 2] int32
    const float* k2d = (const float*)d_in[1];  // [KS, KS] float32
    vfloat4*     out = (vfloat4*)d_out;        // [B, KP, H, H] float32

    heatmap_sweep_kernel<<<NBLOCKS, THREADS, 0, stream>>>(x, k2d, out);
}

// Round 8
// 68.758 us; speedup vs baseline: 1.2264x; 1.2264x over previous
//
#include <hip/hip_runtime.h>

// Problem constants (from reference init_kwargs)
#define BB   64
#define KP   21
#define HH   256
#define KS   9
#define PADK 4   // KS/2

#define NPLANES       (BB * KP)                    // 1344
#define F4_PER_PLANE  (HH * HH / 4)                // 16384
#define NBLOCKS       2048                         // 8 blocks/CU -> 32 waves/CU
#define THREADS       256                          // 4 waves
#define F4_TOTAL      (NPLANES * F4_PER_PLANE)     // 22,020,096
#define F4_PER_BLOCK  (F4_TOTAL / NBLOCKS)         // 10752 (168 KB slice)
#define F4_PER_WAVE   (F4_PER_BLOCK / 4)           // 2688  (42 KB sub-slice)
#define NIT           (F4_PER_WAVE / 64)           // 42 stores per lane

typedef float vfloat4 __attribute__((ext_vector_type(4)));

// Persistent fused zero+patch, PER-WAVE-CONTIGUOUS zero stream: each wave
// owns a sequential 42 KB sub-slice and issues 42 back-to-back 1 KB stores
// at strictly increasing addresses (no reliance on co-scheduling of sibling
// waves for DRAM-sequential traffic). Phase 2 identical to round 6
// (slice-ownership patch overwrite after __syncthreads vmcnt-drain).
__global__ __launch_bounds__(THREADS)
void heatmap_wavecontig_kernel(const int* __restrict__ x,
                               const float* __restrict__ k2d,
                               vfloat4* __restrict__ out) {
    const int t    = threadIdx.x;
    const int wave = t >> 6;
    const int lane = t & 63;
    const int b0   = blockIdx.x * F4_PER_BLOCK;    // first float4 of slice

    // ---- phase 1: per-wave sequential zero stream ----
    vfloat4* ptr = out + b0 + wave * F4_PER_WAVE + lane;
#pragma unroll
    for (int it = 0; it < NIT; ++it) {
        *ptr = (vfloat4)0.0f;                      // wave: 1 KiB contiguous
        ptr += 64;                                 // next 1 KiB, sequential
    }

    __syncthreads();

    // ---- phase 2: patch overwrite within this slice (as round 6) ----
    const int p_lo = b0 / F4_PER_PLANE;
    const int p_hi = (b0 + F4_PER_BLOCK - 1) / F4_PER_PLANE;   // <= p_lo+1

    if (t < KS * KS) {
        const int dy = t / KS;                     // 0..8
        const int dx = t - dy * KS;
        const float wt = 10.0f * k2d[(KS - 1 - dy) * KS + (KS - 1 - dx)];
        for (int p = p_lo; p <= p_hi; ++p) {
            const int r = x[2 * p];
            const int c = x[2 * p + 1];
            const int i = r - PADK + dy;
            const int j = c - PADK + dx;
            if (i < 0 || i >= HH || j < 0 || j >= HH) continue;
            const int g4 = p * F4_PER_PLANE + i * (HH / 4) + (j >> 2);
            if (g4 < b0 || g4 >= b0 + F4_PER_BLOCK) continue;  // not my slice
            ((float*)out)[(size_t)g4 * 4 + (j & 3)] = wt;
        }
    }
}

extern "C" void kernel_launch(void* const* d_in, const int* in_sizes, int n_in,
                              void* d_out, int out_size, void* d_ws, size_t ws_size,
                              hipStream_t stream) {
    const int*   x   = (const int*)d_in[0];    // [B, KP, 2] int32
    const float* k2d = (const float*)d_in[1];  // [KS, KS] float32
    vfloat4*     out = (vfloat4*)d_out;        // [B, KP, H, H] float32

    heatmap_wavecontig_kernel<<<NBLOCKS, THREADS, 0, stream>>>(x, k2d, out);
}